// Round 4
// baseline (138.798 us; speedup 1.0000x reference)
//
#include <hip/hip_runtime.h>
#include <hip/hip_bf16.h>
#include <stdint.h>

// out[e,o] = relu( sum_d (emb[src[e],d] + emb[dst[e],d]) * W[o,d] + b[o] )
// E = 600000, D_IN = D_OUT = 128.
//
// R4: linearity split. P[n,:] = W·emb[n,:] is a tiny 50000x128x128 GEMM
// (bf16 MFMA, fp32 acc) into d_ws; then out[e] = relu(P[src]+P[dst]+b) is a
// pure gather-add-relu stream (no MFMA/LDS/barriers in the hot kernel).
// P (25.6 MB fp32) stays L3-resident across the edge pass (24x avg reuse);
// output stream uses non-temporal stores to avoid evicting it.

using bf16x8 = __attribute__((ext_vector_type(8))) __bf16;
using f32x4  = __attribute__((ext_vector_type(4))) float;
using u16x8  = __attribute__((ext_vector_type(8))) unsigned short;
using u16x4  = __attribute__((ext_vector_type(4))) unsigned short;

static __device__ __forceinline__ unsigned short f2b(float f) {
    return __builtin_bit_cast(unsigned short, (__bf16)f);   // RNE fp32->bf16
}
static __device__ __forceinline__ float b2f(unsigned short u) {
    return __builtin_bit_cast(float, (unsigned int)u << 16); // exact bf16->fp32
}

// ---- P[n,o] = sum_d emb[n,d] * W[o,d]  (bf16 MFMA, fp32 accumulate) ----
// One 64-row tile per block. W staged fp32->bf16 (XOR-swizzled) in LDS.
template<int PF32>
__global__ __launch_bounds__(256, 3) void proj_gemm(
    const float* __restrict__ nodes_f,
    const float* __restrict__ Wf,
    void* __restrict__ proj,
    int n_rows)
{
    __shared__ __align__(16) unsigned short Wt[128 * 128];  // 32 KiB
    __shared__ __align__(16) unsigned short At[64 * 128];   // 16 KiB
    const int tid = threadIdx.x;

    // stage W (bf16, swizzled): B[k=d][n=o] = W[o][d]
    #pragma unroll
    for (int j = 0; j < 8; ++j) {
        int idx = j * 256 + tid;
        int o = idx >> 4;
        int c = idx & 15;
        int elem = o * 128 + c * 8;
        const float4* wp = (const float4*)&Wf[elem];
        float4 a = wp[0], b4 = wp[1];
        u16x8 r;
        r[0] = f2b(a.x);  r[1] = f2b(a.y);  r[2] = f2b(a.z);  r[3] = f2b(a.w);
        r[4] = f2b(b4.x); r[5] = f2b(b4.y); r[6] = f2b(b4.z); r[7] = f2b(b4.w);
        *(u16x8*)&Wt[elem ^ ((o & 7) << 3)] = r;
    }

    const int rbase = blockIdx.x * 64;

    // stage 64 node rows (contiguous, coalesced), fp32->bf16, swizzled
    #pragma unroll
    for (int j = 0; j < 4; ++j) {
        int idx = j * 256 + tid;   // 64 rows * 16 chunks of 8 elems
        int r = idx >> 4;
        int c = idx & 15;
        int row = rbase + r; if (row >= n_rows) row = n_rows - 1;
        const float4* sp = (const float4*)&nodes_f[(size_t)row * 128 + c * 8];
        float4 s0 = sp[0], s1 = sp[1];
        u16x8 v;
        v[0] = f2b(s0.x); v[1] = f2b(s0.y); v[2] = f2b(s0.z); v[3] = f2b(s0.w);
        v[4] = f2b(s1.x); v[5] = f2b(s1.y); v[6] = f2b(s1.z); v[7] = f2b(s1.w);
        *(u16x8*)&At[(r * 128 + c * 8) ^ ((r & 7) << 3)] = v;
    }
    __syncthreads();

    const int wave = tid >> 6;
    const int lane = tid & 63;
    const int lr = lane & 15;
    const int lg = lane >> 4;

    f32x4 acc[8];
    #pragma unroll
    for (int n = 0; n < 8; ++n) acc[n] = (f32x4){0.f, 0.f, 0.f, 0.f};

    const int am = wave * 16 + lr;
    #pragma unroll
    for (int ks = 0; ks < 4; ++ks) {
        bf16x8 af = *(const bf16x8*)&At[(am * 128 + ks * 32 + lg * 8) ^ ((am & 7) << 3)];
        #pragma unroll
        for (int n = 0; n < 8; ++n) {
            const int o = n * 16 + lr;
            bf16x8 bf = *(const bf16x8*)&Wt[(o * 128 + ks * 32 + lg * 8) ^ ((o & 7) << 3)];
            acc[n] = __builtin_amdgcn_mfma_f32_16x16x32_bf16(af, bf, acc[n], 0, 0, 0);
        }
    }

    // store P (REGULAR stores — we want P hot in L2/L3 for the edge pass)
    // C/D map: col = lane&15, row = 4*lg + reg.
    const int r0 = rbase + wave * 16 + lg * 4;
    #pragma unroll
    for (int n = 0; n < 8; ++n) {
        #pragma unroll
        for (int j2 = 0; j2 < 4; ++j2) {
            const int row = r0 + j2;
            if (row < n_rows) {
                if (PF32) {
                    ((float*)proj)[(size_t)row * 128 + n * 16 + lr] = acc[n][j2];
                } else {
                    ((unsigned short*)proj)[(size_t)row * 128 + n * 16 + lr] = f2b(acc[n][j2]);
                }
            }
        }
    }
}

// ---- out[e,:] = relu(P[src[e],:] + P[dst[e],:] + b)  — pure stream ----
// One float4 (16 B) of output per thread per iteration; 32 lanes cover an
// edge row (512 B), fully coalesced on both gather and store sides.
template<int PF32>
__global__ __launch_bounds__(256) void edge_combine(
    const void* __restrict__ proj,
    const int* __restrict__ e_src,
    const int* __restrict__ e_dst,
    const float* __restrict__ bias,
    float* __restrict__ out,
    int E)
{
    const int total4 = E * 32;           // number of float4 outputs
    const int stride = gridDim.x * 256;
    for (int v = blockIdx.x * 256 + threadIdx.x; v < total4; v += stride) {
        const int e = v >> 5;
        const int c = v & 31;
        const int s = e_src[e];
        const int d = e_dst[e];

        f32x4 pa, pb;
        if (PF32) {
            pa = ((const f32x4*)proj)[(size_t)s * 32 + c];
            pb = ((const f32x4*)proj)[(size_t)d * 32 + c];
        } else {
            u16x4 ua = *(const u16x4*)((const unsigned short*)proj + (size_t)s * 128 + c * 4);
            u16x4 ub = *(const u16x4*)((const unsigned short*)proj + (size_t)d * 128 + c * 4);
            #pragma unroll
            for (int q = 0; q < 4; ++q) { pa[q] = b2f(ua[q]); pb[q] = b2f(ub[q]); }
        }
        const f32x4 bb = ((const f32x4*)bias)[c];

        f32x4 r;
        #pragma unroll
        for (int q = 0; q < 4; ++q) {
            float x = pa[q] + pb[q] + bb[q];
            r[q] = x > 0.f ? x : 0.f;
        }
        __builtin_nontemporal_store(r, (f32x4*)&out[(size_t)v * 4]);
    }
}

// ---- fallback (ws too small): R3's fused kernel, fp32 inputs ----
__global__ __launch_bounds__(256, 3) void edge_linear_f(
    const float* __restrict__ nodes_f,
    const int* __restrict__ e_src,
    const int* __restrict__ e_dst,
    const float* __restrict__ Wf,
    const float* __restrict__ bias,
    float* __restrict__ out,
    int E, int ntiles)
{
    __shared__ __align__(16) unsigned short Wt[128 * 128];
    __shared__ __align__(16) unsigned short At[64 * 128];
    const int tid = threadIdx.x;

    #pragma unroll
    for (int j = 0; j < 8; ++j) {
        int idx = j * 256 + tid;
        int o = idx >> 4;
        int c = idx & 15;
        int elem = o * 128 + c * 8;
        const float4* wp = (const float4*)&Wf[elem];
        float4 a = wp[0], b4 = wp[1];
        u16x8 r;
        r[0] = f2b(a.x);  r[1] = f2b(a.y);  r[2] = f2b(a.z);  r[3] = f2b(a.w);
        r[4] = f2b(b4.x); r[5] = f2b(b4.y); r[6] = f2b(b4.z); r[7] = f2b(b4.w);
        *(u16x8*)&Wt[elem ^ ((o & 7) << 3)] = r;
    }

    const int wave = tid >> 6;
    const int lane = tid & 63;
    const int lr = lane & 15;
    const int lg = lane >> 4;

    float bv[8];
    #pragma unroll
    for (int n = 0; n < 8; ++n) bv[n] = bias[n * 16 + lr];

    for (int tile = blockIdx.x; tile < ntiles; tile += gridDim.x) {
        const int ebase = tile * 64;
        #pragma unroll
        for (int j = 0; j < 4; ++j) {
            int idx = j * 256 + tid;
            int e = idx >> 4;
            int c = idx & 15;
            int eg = ebase + e; if (eg >= E) eg = E - 1;
            int s = e_src[eg], d = e_dst[eg];
            const float4* sp = (const float4*)&nodes_f[(size_t)s * 128 + c * 8];
            const float4* dp = (const float4*)&nodes_f[(size_t)d * 128 + c * 8];
            float4 s0 = sp[0], s1 = sp[1], d0 = dp[0], d1 = dp[1];
            u16x8 r;
            r[0] = f2b(s0.x + d0.x); r[1] = f2b(s0.y + d0.y);
            r[2] = f2b(s0.z + d0.z); r[3] = f2b(s0.w + d0.w);
            r[4] = f2b(s1.x + d1.x); r[5] = f2b(s1.y + d1.y);
            r[6] = f2b(s1.z + d1.z); r[7] = f2b(s1.w + d1.w);
            *(u16x8*)&At[(e * 128 + c * 8) ^ ((e & 7) << 3)] = r;
        }
        __syncthreads();

        f32x4 acc[8];
        #pragma unroll
        for (int n = 0; n < 8; ++n) acc[n] = (f32x4){0.f, 0.f, 0.f, 0.f};

        const int am = wave * 16 + lr;
        #pragma unroll
        for (int ks = 0; ks < 4; ++ks) {
            bf16x8 af = *(const bf16x8*)&At[(am * 128 + ks * 32 + lg * 8) ^ ((am & 7) << 3)];
            #pragma unroll
            for (int n = 0; n < 8; ++n) {
                const int o = n * 16 + lr;
                bf16x8 bf = *(const bf16x8*)&Wt[(o * 128 + ks * 32 + lg * 8) ^ ((o & 7) << 3)];
                acc[n] = __builtin_amdgcn_mfma_f32_16x16x32_bf16(af, bf, acc[n], 0, 0, 0);
            }
        }

        const int er0 = ebase + wave * 16 + lg * 4;
        #pragma unroll
        for (int n = 0; n < 8; ++n) {
            #pragma unroll
            for (int j2 = 0; j2 < 4; ++j2) {
                const int e = er0 + j2;
                if (e < E) {
                    float v = acc[n][j2] + bv[n];
                    v = v > 0.f ? v : 0.f;
                    __builtin_nontemporal_store(v, &out[(size_t)e * 128 + n * 16 + lr]);
                }
            }
        }
        __syncthreads();
    }
}

extern "C" void kernel_launch(void* const* d_in, const int* in_sizes, int n_in,
                              void* d_out, int out_size, void* d_ws, size_t ws_size,
                              hipStream_t stream) {
    const float* nodes = (const float*)d_in[0];
    const int*   ei    = (const int*)d_in[1];     // [2][E] int32: row0=src, row1=dst
    const float* W     = (const float*)d_in[2];   // [128][128] fp32, row-major [o][d]
    const float* bias  = (const float*)d_in[3];   // [128] fp32
    float* out = (float*)d_out;

    const int n_node = in_sizes[0];               // 50000*128 elements
    const int E      = in_sizes[1] / 2;           // 600000
    const int n_rows = n_node / 128;              // 50000

    const int gblocks = (n_rows + 63) / 64;       // 782
    int cblocks = (E * 32 + 255) / 256;
    if (cblocks > 2048) cblocks = 2048;

    if (ws_size >= (size_t)n_node * 4) {
        proj_gemm<1><<<gblocks, 256, 0, stream>>>(nodes, W, d_ws, n_rows);
        edge_combine<1><<<cblocks, 256, 0, stream>>>(d_ws, ei, ei + E, bias, out, E);
    } else if (ws_size >= (size_t)n_node * 2) {
        proj_gemm<0><<<gblocks, 256, 0, stream>>>(nodes, W, d_ws, n_rows);
        edge_combine<0><<<cblocks, 256, 0, stream>>>(d_ws, ei, ei + E, bias, out, E);
    } else {
        const int ntiles = (E + 63) / 64;
        int blocks = ntiles < 768 ? ntiles : 768;
        edge_linear_f<<<blocks, 256, 0, stream>>>(nodes, ei, ei + E, W, bias,
                                                  out, E, ntiles);
    }
}

// Round 5
// 96.139 us; speedup vs baseline: 1.4437x; 1.4437x over previous
//
#include <hip/hip_runtime.h>
#include <hip/hip_bf16.h>
#include <stdint.h>

// out[e,o] = relu( sum_d (emb[src[e],d] + emb[dst[e],d]) * W[o,d] + b[o] )
// E = 600000, D_IN = D_OUT = 128.
//
// R5: linearity split with BF16 P. P[n,:] = W·emb[n,:] (bf16 MFMA GEMM) is
// stored as bf16 (12.8 MB) in d_ws; the hot kernel streams
// out[e] = relu(P[src]+P[dst]+b) with 256-B/edge gathers (halved vs fp32 P)
// and 512-B/edge nt stores. Evidence from R2-R4: gathers pay ~full HBM price
// regardless of nt hints, so minimize gather BYTES; pure-stream structure
// runs at ~6.7 TB/s mixed BW.

using bf16x8 = __attribute__((ext_vector_type(8))) __bf16;
using f32x4  = __attribute__((ext_vector_type(4))) float;
using u16x8  = __attribute__((ext_vector_type(8))) unsigned short;
using u16x4  = __attribute__((ext_vector_type(4))) unsigned short;

static __device__ __forceinline__ unsigned short f2b(float f) {
    return __builtin_bit_cast(unsigned short, (__bf16)f);   // RNE fp32->bf16
}
static __device__ __forceinline__ float b2f(unsigned short u) {
    return __builtin_bit_cast(float, (unsigned int)u << 16); // exact bf16->fp32
}

// ---- P[n,o] = sum_d emb[n,d] * W[o,d]  (bf16 MFMA, fp32 acc, bf16 store) ----
__global__ __launch_bounds__(256, 3) void proj_gemm(
    const float* __restrict__ nodes_f,
    const float* __restrict__ Wf,
    unsigned short* __restrict__ proj,   // bf16 out [n_rows][128]
    int n_rows)
{
    __shared__ __align__(16) unsigned short Wt[128 * 128];  // 32 KiB
    __shared__ __align__(16) unsigned short At[64 * 128];   // 16 KiB
    const int tid = threadIdx.x;

    // stage W (bf16, XOR-swizzled): B[k=d][n=o] = W[o][d]
    #pragma unroll
    for (int j = 0; j < 8; ++j) {
        int idx = j * 256 + tid;
        int o = idx >> 4;
        int c = idx & 15;
        int elem = o * 128 + c * 8;
        const float4* wp = (const float4*)&Wf[elem];
        float4 a = wp[0], b4 = wp[1];
        u16x8 r;
        r[0] = f2b(a.x);  r[1] = f2b(a.y);  r[2] = f2b(a.z);  r[3] = f2b(a.w);
        r[4] = f2b(b4.x); r[5] = f2b(b4.y); r[6] = f2b(b4.z); r[7] = f2b(b4.w);
        *(u16x8*)&Wt[elem ^ ((o & 7) << 3)] = r;
    }

    const int rbase = blockIdx.x * 64;

    // stage 64 node rows (contiguous, coalesced), fp32->bf16, swizzled
    #pragma unroll
    for (int j = 0; j < 4; ++j) {
        int idx = j * 256 + tid;   // 64 rows * 16 chunks of 8 elems
        int r = idx >> 4;
        int c = idx & 15;
        int row = rbase + r; if (row >= n_rows) row = n_rows - 1;
        const float4* sp = (const float4*)&nodes_f[(size_t)row * 128 + c * 8];
        float4 s0 = sp[0], s1 = sp[1];
        u16x8 v;
        v[0] = f2b(s0.x); v[1] = f2b(s0.y); v[2] = f2b(s0.z); v[3] = f2b(s0.w);
        v[4] = f2b(s1.x); v[5] = f2b(s1.y); v[6] = f2b(s1.z); v[7] = f2b(s1.w);
        *(u16x8*)&At[(r * 128 + c * 8) ^ ((r & 7) << 3)] = v;
    }
    __syncthreads();

    const int wave = tid >> 6;
    const int lane = tid & 63;
    const int lr = lane & 15;
    const int lg = lane >> 4;

    f32x4 acc[8];
    #pragma unroll
    for (int n = 0; n < 8; ++n) acc[n] = (f32x4){0.f, 0.f, 0.f, 0.f};

    const int am = wave * 16 + lr;
    #pragma unroll
    for (int ks = 0; ks < 4; ++ks) {
        bf16x8 af = *(const bf16x8*)&At[(am * 128 + ks * 32 + lg * 8) ^ ((am & 7) << 3)];
        #pragma unroll
        for (int n = 0; n < 8; ++n) {
            const int o = n * 16 + lr;
            bf16x8 bf = *(const bf16x8*)&Wt[(o * 128 + ks * 32 + lg * 8) ^ ((o & 7) << 3)];
            acc[n] = __builtin_amdgcn_mfma_f32_16x16x32_bf16(af, bf, acc[n], 0, 0, 0);
        }
    }

    // store P as bf16. C/D map: col = lane&15, row = 4*lg + reg.
    const int r0 = rbase + wave * 16 + lg * 4;
    #pragma unroll
    for (int n = 0; n < 8; ++n) {
        #pragma unroll
        for (int j2 = 0; j2 < 4; ++j2) {
            const int row = r0 + j2;
            if (row < n_rows)
                proj[(size_t)row * 128 + n * 16 + lr] = f2b(acc[n][j2]);
        }
    }
}

// ---- out[e,:] = relu(P[src[e],:] + P[dst[e],:] + b)  — pure stream ----
// One lane per 4 output floats: 8-B bf16 gather/lane (32 lanes cover an
// edge's 256-B P row), 16-B fp32 nt store/lane (contiguous 512-B row).
// Grid stride is a multiple of 32 -> c (and the bias chunk) is loop-invariant.
__global__ __launch_bounds__(256) void edge_combine(
    const unsigned short* __restrict__ proj,
    const int* __restrict__ e_src,
    const int* __restrict__ e_dst,
    const float* __restrict__ bias,
    float* __restrict__ out,
    int E)
{
    const int total4 = E * 32;           // number of float4 outputs
    const int stride = gridDim.x * 256;  // multiple of 32
    int v = blockIdx.x * 256 + threadIdx.x;
    if (v >= total4) return;
    const int c = v & 31;                // float4 chunk within row (invariant)
    const f32x4 bb = ((const f32x4*)bias)[c];

    for (; v < total4; v += stride) {
        const int e = v >> 5;
        const int s = e_src[e];
        const int d = e_dst[e];

        u16x4 ua = *(const u16x4*)&proj[(size_t)s * 128 + c * 4];
        u16x4 ub = *(const u16x4*)&proj[(size_t)d * 128 + c * 4];

        f32x4 r;
        #pragma unroll
        for (int q = 0; q < 4; ++q) {
            float x = b2f(ua[q]) + b2f(ub[q]) + bb[q];
            r[q] = x > 0.f ? x : 0.f;
        }
        __builtin_nontemporal_store(r, (f32x4*)&out[(size_t)v * 4]);
    }
}

// ---- fallback (ws too small): fused kernel, fp32 inputs ----
__global__ __launch_bounds__(256, 3) void edge_linear_f(
    const float* __restrict__ nodes_f,
    const int* __restrict__ e_src,
    const int* __restrict__ e_dst,
    const float* __restrict__ Wf,
    const float* __restrict__ bias,
    float* __restrict__ out,
    int E, int ntiles)
{
    __shared__ __align__(16) unsigned short Wt[128 * 128];
    __shared__ __align__(16) unsigned short At[64 * 128];
    const int tid = threadIdx.x;

    #pragma unroll
    for (int j = 0; j < 8; ++j) {
        int idx = j * 256 + tid;
        int o = idx >> 4;
        int c = idx & 15;
        int elem = o * 128 + c * 8;
        const float4* wp = (const float4*)&Wf[elem];
        float4 a = wp[0], b4 = wp[1];
        u16x8 r;
        r[0] = f2b(a.x);  r[1] = f2b(a.y);  r[2] = f2b(a.z);  r[3] = f2b(a.w);
        r[4] = f2b(b4.x); r[5] = f2b(b4.y); r[6] = f2b(b4.z); r[7] = f2b(b4.w);
        *(u16x8*)&Wt[elem ^ ((o & 7) << 3)] = r;
    }

    const int wave = tid >> 6;
    const int lane = tid & 63;
    const int lr = lane & 15;
    const int lg = lane >> 4;

    float bv[8];
    #pragma unroll
    for (int n = 0; n < 8; ++n) bv[n] = bias[n * 16 + lr];

    for (int tile = blockIdx.x; tile < ntiles; tile += gridDim.x) {
        const int ebase = tile * 64;
        #pragma unroll
        for (int j = 0; j < 4; ++j) {
            int idx = j * 256 + tid;
            int e = idx >> 4;
            int c = idx & 15;
            int eg = ebase + e; if (eg >= E) eg = E - 1;
            int s = e_src[eg], d = e_dst[eg];
            const float4* sp = (const float4*)&nodes_f[(size_t)s * 128 + c * 8];
            const float4* dp = (const float4*)&nodes_f[(size_t)d * 128 + c * 8];
            float4 s0 = sp[0], s1 = sp[1], d0 = dp[0], d1 = dp[1];
            u16x8 r;
            r[0] = f2b(s0.x + d0.x); r[1] = f2b(s0.y + d0.y);
            r[2] = f2b(s0.z + d0.z); r[3] = f2b(s0.w + d0.w);
            r[4] = f2b(s1.x + d1.x); r[5] = f2b(s1.y + d1.y);
            r[6] = f2b(s1.z + d1.z); r[7] = f2b(s1.w + d1.w);
            *(u16x8*)&At[(e * 128 + c * 8) ^ ((e & 7) << 3)] = r;
        }
        __syncthreads();

        f32x4 acc[8];
        #pragma unroll
        for (int n = 0; n < 8; ++n) acc[n] = (f32x4){0.f, 0.f, 0.f, 0.f};

        const int am = wave * 16 + lr;
        #pragma unroll
        for (int ks = 0; ks < 4; ++ks) {
            bf16x8 af = *(const bf16x8*)&At[(am * 128 + ks * 32 + lg * 8) ^ ((am & 7) << 3)];
            #pragma unroll
            for (int n = 0; n < 8; ++n) {
                const int o = n * 16 + lr;
                bf16x8 bf = *(const bf16x8*)&Wt[(o * 128 + ks * 32 + lg * 8) ^ ((o & 7) << 3)];
                acc[n] = __builtin_amdgcn_mfma_f32_16x16x32_bf16(af, bf, acc[n], 0, 0, 0);
            }
        }

        const int er0 = ebase + wave * 16 + lg * 4;
        #pragma unroll
        for (int n = 0; n < 8; ++n) {
            #pragma unroll
            for (int j2 = 0; j2 < 4; ++j2) {
                const int e = er0 + j2;
                if (e < E) {
                    float v = acc[n][j2] + bv[n];
                    v = v > 0.f ? v : 0.f;
                    __builtin_nontemporal_store(v, &out[(size_t)e * 128 + n * 16 + lr]);
                }
            }
        }
        __syncthreads();
    }
}

extern "C" void kernel_launch(void* const* d_in, const int* in_sizes, int n_in,
                              void* d_out, int out_size, void* d_ws, size_t ws_size,
                              hipStream_t stream) {
    const float* nodes = (const float*)d_in[0];
    const int*   ei    = (const int*)d_in[1];     // [2][E] int32: row0=src, row1=dst
    const float* W     = (const float*)d_in[2];   // [128][128] fp32, row-major [o][d]
    const float* bias  = (const float*)d_in[3];   // [128] fp32
    float* out = (float*)d_out;

    const int n_node = in_sizes[0];               // 50000*128 elements
    const int E      = in_sizes[1] / 2;           // 600000
    const int n_rows = n_node / 128;              // 50000

    if (ws_size >= (size_t)n_node * 2) {
        unsigned short* proj = (unsigned short*)d_ws;
        const int gblocks = (n_rows + 63) / 64;   // 782
        int cblocks = (E * 32 + 255) / 256;
        if (cblocks > 2048) cblocks = 2048;
        proj_gemm<<<gblocks, 256, 0, stream>>>(nodes, W, proj, n_rows);
        edge_combine<<<cblocks, 256, 0, stream>>>(proj, ei, ei + E, bias, out, E);
    } else {
        const int ntiles = (E + 63) / 64;
        int blocks = ntiles < 768 ? ntiles : 768;
        edge_linear_f<<<blocks, 256, 0, stream>>>(nodes, ei, ei + E, W, bias,
                                                  out, E, ntiles);
    }
}